// Round 5
// baseline (2065.013 us; speedup 1.0000x reference)
//
#include <hip/hip_runtime.h>

// StructuredLSNN v5: exact f32 semantics match vs numpy reference.
// Round-4: out0 PASSED (d_out is f32), out1 absmax = 1.0 (spike flips).
// Root cause: reference resets mem via mem*(1-spk) -> for mem=+inf this is
// inf*0 = NaN (poisons the unit forever); I reset to 0, so my units kept
// spiking for the 1-3 steps where cur=+-inf but state still finite.
// Fix: replicate mem = mem*(1-spk) exactly, plus BLAS-order arithmetic:
//   - dot products: k-sequential single-accumulator FMA chain starting at 0
//   - bias/u*B added AFTER the chain (separate rounding)
//   - mem = 0.9*mem + cur two-rounded (no FMA contraction): __fmul_rn/__fadd_rn
// Structure: 1 block/batch, 256 threads. Wave0 = SSM producer (state in lane
// registers, v_readlane broadcasts, 64-FMA sequential chain/step, writes 64x64
// chunk tile to LDS). Waves1-3 = 192 LIF units (enc row in VGPRs, sequential
// chain over broadcast LDS reads). Double-buffered tiles, 1 barrier/chunk.

#define TT 4096
#define NBATCH 256
#define HH 192
#define CS 64
#define NC (TT / CS)

__global__ __launch_bounds__(256) void lsnn_fused(
    const float* __restrict__ x,
    const float* __restrict__ A,
    const float* __restrict__ Bv,
    const float* __restrict__ enc_w,
    const float* __restrict__ enc_b,
    const float* __restrict__ ro_w,
    const float* __restrict__ ro_b,
    float* __restrict__ out0,
    float* __restrict__ out1)
{
    __shared__ __align__(16) float st[2][CS * 64];   // chunk state tiles [q][d]
    __shared__ __align__(16) float xb[TT];           // this batch's input
    __shared__ float stg[64 * 17];                   // A-row staging strips
    __shared__ float rate[HH];

    const int tid = threadIdx.x;
    const int b = blockIdx.x;

    // ---- stage x[b][:] ----
    {
        const float4* xs = (const float4*)(x + (size_t)b * TT);
        float4* xd = (float4*)xb;
        for (int e = tid; e < TT / 4; e += 256) xd[e] = xs[e];
    }

    // ---- producer: A row tid into VGPRs (16-col LDS strips) ----
    float ar[64];
    for (int s = 0; s < 4; ++s) {
        for (int e = tid; e < 1024; e += 256)
            stg[(e >> 4) * 17 + (e & 15)] = A[(e >> 4) * 64 + s * 16 + (e & 15)];
        __syncthreads();
        if (tid < 64) {
            #pragma unroll
            for (int k = 0; k < 16; ++k) ar[s * 16 + k] = stg[tid * 17 + k];
        }
        __syncthreads();
    }

    // ---- consumer: enc_w row into VGPRs ----
    float w[64];
    float bias = 0.f;
    const int h = tid - 64;                 // consumer lane id 0..191
    if (h >= 0) {
        #pragma unroll
        for (int k = 0; k < 16; ++k) {
            float4 t4 = *(const float4*)(enc_w + (size_t)h * 64 + k * 4);
            w[4 * k] = t4.x; w[4 * k + 1] = t4.y; w[4 * k + 2] = t4.z; w[4 * k + 3] = t4.w;
        }
        bias = enc_b[h];
    }
    float bi = 0.f;
    if (tid < 64) bi = Bv[tid];

    float s_cur = 0.f;                      // producer: lane tid holds state[tid]

    // producer: build chunk j into st[sel]; state crosses lanes via readlane
    auto build_chunk = [&](int j, int sel) {
        float* dst = st[sel];
        const float* xc = xb + j * CS;
        for (int q = 0; q < CS; ++q) {
            float acc = 0.f;
            #pragma unroll
            for (int k = 0; k < 64; ++k) {
                const float sk = __int_as_float(
                    __builtin_amdgcn_readlane(__float_as_int(s_cur), k));
                acc = fmaf(ar[k], sk, acc);          // k-sequential FMA chain
            }
            const float ns = __fadd_rn(acc, __fmul_rn(bi, xc[q]));  // + (u*B) rounded sep.
            dst[q * 64 + tid] = ns;
            s_cur = ns;
        }
    };

    float mem = 0.f, cnt = 0.f;
    auto consume_chunk = [&](int j, int sel) {
        const float* src = st[sel];
        float* o = out1 + ((size_t)b * TT + (size_t)j * CS) * HH + h;
        #pragma unroll 2
        for (int t = 0; t < CS; ++t) {
            const float* sp = src + t * 64;
            float acc = 0.f;
            #pragma unroll
            for (int k = 0; k < 64; ++k)
                acc = fmaf(w[k], sp[k], acc);        // k-sequential FMA chain
            const float cur = __fadd_rn(acc, bias);  // bias added after (BLAS epilogue)
            mem = __fadd_rn(__fmul_rn(0.9f, mem), cur);   // two-rounded, no FMA
            const float sv = (mem > 1.0f) ? 1.0f : 0.0f;  // == (mem-1>0) in f32
            o[(size_t)t * HH] = sv;
            mem = __fmul_rn(mem, __fsub_rn(1.0f, sv));    // inf*0 = NaN, as reference
            cnt += sv;
        }
    };

    // ---- pipeline: producer one chunk ahead ----
    if (tid < 64) build_chunk(0, 0);
    __syncthreads();
    for (int j = 0; j < NC; ++j) {
        if (tid < 64) {
            if (j + 1 < NC) build_chunk(j + 1, (j + 1) & 1);
        } else {
            consume_chunk(j, j & 1);
        }
        __syncthreads();
    }

    // ---- rate + readout ----
    if (h >= 0) rate[h] = cnt * (1.0f / 4096.0f);   // exact (integer cnt, pow2 divide)
    __syncthreads();
    if (tid < 10) {
        float acc = 0.f;
        for (int k = 0; k < HH; ++k) acc = fmaf(ro_w[tid * HH + k], rate[k], acc);
        out0[b * 10 + tid] = __fadd_rn(acc, ro_b[tid]);
    }
}

extern "C" void kernel_launch(void* const* d_in, const int* in_sizes, int n_in,
                              void* d_out, int out_size, void* d_ws, size_t ws_size,
                              hipStream_t stream) {
    (void)out_size; (void)d_ws; (void)ws_size;
    // size-based input mapping (all seven sizes unique)
    // x:1048576  enc_w:12288  enc_b:192  ro_w:1920  ro_b:10  A:4096  B:64
    const void* px = nullptr; const void* pew = nullptr; const void* peb = nullptr;
    const void* prw = nullptr; const void* prb = nullptr; const void* pA = nullptr;
    const void* pB = nullptr;
    for (int i = 0; i < n_in; ++i) {
        switch (in_sizes[i]) {
            case 1048576: px  = d_in[i]; break;
            case 12288:   pew = d_in[i]; break;
            case 192:     peb = d_in[i]; break;
            case 1920:    prw = d_in[i]; break;
            case 10:      prb = d_in[i]; break;
            case 4096:    pA  = d_in[i]; break;
            case 64:      pB  = d_in[i]; break;
            default: break;
        }
    }
    if (!px || !pew || !peb || !prw || !prb || !pA || !pB) {
        px = d_in[0]; pew = d_in[1]; peb = d_in[2];
        prw = d_in[3]; prb = d_in[4]; pA = d_in[5]; pB = d_in[6];
    }
    const float* x     = (const float*)px;
    const float* enc_w = (const float*)pew;
    const float* enc_b = (const float*)peb;
    const float* ro_w  = (const float*)prw;
    const float* ro_b  = (const float*)prb;
    const float* A     = (const float*)pA;
    const float* Bv    = (const float*)pB;
    float* out0 = (float*)d_out;
    float* out1 = out0 + NBATCH * 10;

    lsnn_fused<<<NBATCH, 256, 0, stream>>>(x, A, Bv, enc_w, enc_b, ro_w, ro_b, out0, out1);
}

// Round 6
// 1969.524 us; speedup vs baseline: 1.0485x; 1.0485x over previous
//
#include <hip/hip_runtime.h>

// StructuredLSNN v6: v5 (bit-exact, absmax=0) + spill elimination + consumer ILP.
// v5 post-mortem: FETCH_SIZE=2399MB (vs ~29MB input) with VGPR_Count=80 ->
// ar[64]+w[64] both live all-kernel => compiler spilled them to scratch and
// reloaded per step inside the dependent FMA chains (1242 cyc/step measured).
// Fix 1: single shared row[64] array — producer wave loads A-row, consumer
//        waves load enc_w-row (never coexist per-thread) -> no spill.
// Fix 2: consumer processes 2 timesteps per iteration: 32 ds_read_b128 staged
//        up-front, two interleaved k-sequential FMA chains (per-chain order
//        unchanged -> spikes stay bit-exact); chain latencies overlap.
// Producer floor = 4096 steps x 64 dependent FMA x 4cyc = 437us (serial SSM).

#define TT 4096
#define NBATCH 256
#define HH 192
#define CS 64
#define NC (TT / CS)

__global__ __launch_bounds__(256) void lsnn_fused(
    const float* __restrict__ x,
    const float* __restrict__ A,
    const float* __restrict__ Bv,
    const float* __restrict__ enc_w,
    const float* __restrict__ enc_b,
    const float* __restrict__ ro_w,
    const float* __restrict__ ro_b,
    float* __restrict__ out0,
    float* __restrict__ out1)
{
    __shared__ __align__(16) float st[2][CS * 64];   // chunk state tiles [q][d]
    __shared__ __align__(16) float xb[TT];           // this batch's input
    __shared__ float rate[HH];

    const int tid = threadIdx.x;
    const int b = blockIdx.x;
    const int h = tid - 64;                 // consumer lane id 0..191 (tid>=64)

    // ---- stage x[b][:] ----
    {
        const float4* xs = (const float4*)(x + (size_t)b * TT);
        float4* xd = (float4*)xb;
        for (int e = tid; e < TT / 4; e += 256) xd[e] = xs[e];
    }

    // ---- shared row registers: A row (producer wave) / enc_w row (consumers) ----
    float row[64];
    {
        const float* rsrc = (tid < 64) ? (A + (size_t)tid * 64)
                                       : (enc_w + (size_t)h * 64);
        #pragma unroll
        for (int q = 0; q < 16; ++q) {
            float4 t4 = ((const float4*)rsrc)[q];
            row[4 * q]     = t4.x;
            row[4 * q + 1] = t4.y;
            row[4 * q + 2] = t4.z;
            row[4 * q + 3] = t4.w;
        }
    }
    const float bias = (h >= 0) ? enc_b[h] : 0.f;
    const float bi   = (tid < 64) ? Bv[tid] : 0.f;

    float s_cur = 0.f;                      // producer: lane tid holds state[tid]

    // producer: build chunk j into st[sel]; state crosses lanes via readlane
    auto build_chunk = [&](int j, int sel) {
        float* dst = st[sel];
        const float* xc = xb + j * CS;
        for (int q = 0; q < CS; ++q) {
            float acc = 0.f;
            #pragma unroll
            for (int k = 0; k < 64; ++k) {
                const float sk = __int_as_float(
                    __builtin_amdgcn_readlane(__float_as_int(s_cur), k));
                acc = fmaf(row[k], sk, acc);         // k-sequential FMA chain
            }
            const float ns = __fadd_rn(acc, __fmul_rn(bi, xc[q]));
            dst[q * 64 + tid] = ns;
            s_cur = ns;
        }
    };

    float mem = 0.f, cnt = 0.f;
    // consumer: LIF over chunk j; 2-timestep ILP, k-sequential chains
    auto consume_chunk = [&](int j, int sel) {
        const float* src = st[sel];
        float* o = out1 + ((size_t)b * TT + (size_t)j * CS) * HH + h;
        for (int t = 0; t < CS; t += 2) {
            const float4* p0 = (const float4*)(src + t * 64);
            const float4* p1 = (const float4*)(src + (t + 1) * 64);
            float4 r0[16], r1[16];
            #pragma unroll
            for (int q = 0; q < 16; ++q) r0[q] = p0[q];
            #pragma unroll
            for (int q = 0; q < 16; ++q) r1[q] = p1[q];
            float acc0 = 0.f, acc1 = 0.f;
            #pragma unroll
            for (int q = 0; q < 16; ++q) {          // two independent chains, interleaved
                acc0 = fmaf(row[4 * q],     r0[q].x, acc0);
                acc1 = fmaf(row[4 * q],     r1[q].x, acc1);
                acc0 = fmaf(row[4 * q + 1], r0[q].y, acc0);
                acc1 = fmaf(row[4 * q + 1], r1[q].y, acc1);
                acc0 = fmaf(row[4 * q + 2], r0[q].z, acc0);
                acc1 = fmaf(row[4 * q + 2], r1[q].z, acc1);
                acc0 = fmaf(row[4 * q + 3], r0[q].w, acc0);
                acc1 = fmaf(row[4 * q + 3], r1[q].w, acc1);
            }
            // LIF step t
            float cur = __fadd_rn(acc0, bias);
            mem = __fadd_rn(__fmul_rn(0.9f, mem), cur);
            float sv = (mem > 1.0f) ? 1.0f : 0.0f;
            o[(size_t)t * HH] = sv;
            mem = __fmul_rn(mem, __fsub_rn(1.0f, sv));   // inf*0=NaN as reference
            cnt += sv;
            // LIF step t+1
            cur = __fadd_rn(acc1, bias);
            mem = __fadd_rn(__fmul_rn(0.9f, mem), cur);
            sv = (mem > 1.0f) ? 1.0f : 0.0f;
            o[(size_t)(t + 1) * HH] = sv;
            mem = __fmul_rn(mem, __fsub_rn(1.0f, sv));
            cnt += sv;
        }
    };

    // ---- pipeline: producer one chunk ahead ----
    if (tid < 64) build_chunk(0, 0);
    __syncthreads();
    for (int j = 0; j < NC; ++j) {
        if (tid < 64) {
            if (j + 1 < NC) build_chunk(j + 1, (j + 1) & 1);
        } else {
            consume_chunk(j, j & 1);
        }
        __syncthreads();
    }

    // ---- rate + readout ----
    if (h >= 0) rate[h] = cnt * (1.0f / 4096.0f);   // exact (integer cnt, pow2 divide)
    __syncthreads();
    if (tid < 10) {
        float acc = 0.f;
        for (int k = 0; k < HH; ++k) acc = fmaf(ro_w[tid * HH + k], rate[k], acc);
        out0[b * 10 + tid] = __fadd_rn(acc, ro_b[tid]);
    }
}

extern "C" void kernel_launch(void* const* d_in, const int* in_sizes, int n_in,
                              void* d_out, int out_size, void* d_ws, size_t ws_size,
                              hipStream_t stream) {
    (void)out_size; (void)d_ws; (void)ws_size;
    // size-based input mapping (all seven sizes unique)
    // x:1048576  enc_w:12288  enc_b:192  ro_w:1920  ro_b:10  A:4096  B:64
    const void* px = nullptr; const void* pew = nullptr; const void* peb = nullptr;
    const void* prw = nullptr; const void* prb = nullptr; const void* pA = nullptr;
    const void* pB = nullptr;
    for (int i = 0; i < n_in; ++i) {
        switch (in_sizes[i]) {
            case 1048576: px  = d_in[i]; break;
            case 12288:   pew = d_in[i]; break;
            case 192:     peb = d_in[i]; break;
            case 1920:    prw = d_in[i]; break;
            case 10:      prb = d_in[i]; break;
            case 4096:    pA  = d_in[i]; break;
            case 64:      pB  = d_in[i]; break;
            default: break;
        }
    }
    if (!px || !pew || !peb || !prw || !prb || !pA || !pB) {
        px = d_in[0]; pew = d_in[1]; peb = d_in[2];
        prw = d_in[3]; prb = d_in[4]; pA = d_in[5]; pB = d_in[6];
    }
    const float* x     = (const float*)px;
    const float* enc_w = (const float*)pew;
    const float* enc_b = (const float*)peb;
    const float* ro_w  = (const float*)prw;
    const float* ro_b  = (const float*)prb;
    const float* A     = (const float*)pA;
    const float* Bv    = (const float*)pB;
    float* out0 = (float*)d_out;
    float* out1 = out0 + NBATCH * 10;

    lsnn_fused<<<NBATCH, 256, 0, stream>>>(x, A, Bv, enc_w, enc_b, ro_w, ro_b, out0, out1);
}